// Round 4
// baseline (1704.235 us; speedup 1.0000x reference)
//
#include <hip/hip_runtime.h>
#include <hip/hip_cooperative_groups.h>

// ChebClassifier R13: collapse the 27-kernel serial chain into 8 dispatches.
// Cooperative kernels with grid.sync() merge same-occupancy-class phases:
//   coop_build      = prep + c1 + c2a + c2b + c3 + dcsr     (grid 637)
//   coop_prop0      = 5x level-0 Chebyshev steps            (grid 391)
//   coop_pool_prop1 = pool0 + 5x level-1 steps              (grid 512)
//   coop_pool_prop2 = pool1 + 5x level-2 steps              (grid 512)
// h0_mfma / gemm1 / gemm2 / linear stay standalone (high VGPR/LDS class).
// Math identical to R12 (fp16 side-channel, fp32 recurrence state).

namespace cg = cooperative_groups;

namespace {
constexpr int cN0 = 100000, cN1 = 25000, cN2 = 6250;
constexpr int cE0 = 600000, cE1 = 150000, cE2 = 37500;
constexpr int cD  = cN2 * 256;

constexpr int JN[5]  = {cN0, cN1, cN2, cN1, cN2};
constexpr int JE[5]  = {cE0, cE1, cE2, 100000, 25000};
constexpr int JB[5]  = {391, 98, 25, 98, 25};
constexpr int JBBASE[6] = {0, 391, 489, 514, 612, 637};
constexpr int TB = 637;
constexpr int JCB[5] = {293, 74, 19, 49, 13};
constexpr int JCBASE[6] = {0, 293, 367, 386, 435, 448};
constexpr int TCB = 448;
constexpr int CHUNK = 2048;
constexpr int BSTRIDE = 400;

constexpr int EBASE[5]   = {0, 600000, 750000, 787500, 887500};
constexpr int E_TOTAL    = 912500;
constexpr int NBASE[5]   = {0, 100096, 125184, 131584, 156672};
constexpr int NPAD_TOTAL = 163072;
constexpr int DEGBASE[3] = {0, 100000, 125000};
constexpr int DEG_TOTAL  = 131250;
constexpr int WPREP_TOTAL = 768 * 128 + 768 * 256 + 128 * 32;
constexpr int PREP_ALL_TOTAL = WPREP_TOTAL + DEG_TOTAL + cN0 + 10;
}

typedef __attribute__((ext_vector_type(8))) short short8;
typedef __attribute__((ext_vector_type(4))) float floatx4;

__device__ inline ushort f2h(float f) {
  union { _Float16 h; ushort u; } v;
  v.h = (_Float16)f;
  return v.u;
}
__device__ inline float h2f(unsigned lo16) {
  union { ushort u; _Float16 h; } v;
  v.u = (ushort)lo16;
  return (float)v.h;
}

__device__ inline int job_of_cb(int cb) {
  int j = 0;
  while (cb >= JCBASE[j + 1]) ++j;
  return j;
}
__device__ inline int job_of_bucket(int g) {
  int j = 0;
  while (g >= JBBASE[j + 1]) ++j;
  return j;
}

// ---------------- row workers ----------------
__device__ __forceinline__ void prop3_row(
    const int* __restrict__ off, const int2* __restrict__ pairs,
    const float4* __restrict__ h, float4* __restrict__ y,
    const float4* __restrict__ prev, float scale,
    ushort* __restrict__ yh, int kslot, int r) {
  int s = off[r], e = off[r + 1];
  float ax = 0.f, ay = 0.f, az = 0.f;
  int j = s;
  for (; j + 4 <= e; j += 4) {
    int2 p0 = pairs[j], p1 = pairs[j + 1], p2 = pairs[j + 2], p3 = pairs[j + 3];
    float4 h0 = h[p0.x], h1 = h[p1.x], h2 = h[p2.x], h3 = h[p3.x];
    float w0 = __int_as_float(p0.y), w1 = __int_as_float(p1.y);
    float w2 = __int_as_float(p2.y), w3 = __int_as_float(p3.y);
    ax += w0 * h0.x + w1 * h1.x + w2 * h2.x + w3 * h3.x;
    ay += w0 * h0.y + w1 * h1.y + w2 * h2.y + w3 * h3.y;
    az += w0 * h0.z + w1 * h1.z + w2 * h2.z + w3 * h3.z;
  }
  for (; j < e; ++j) {
    int2 p = pairs[j];
    float4 hv = h[p.x];
    float w = __int_as_float(p.y);
    ax += w * hv.x; ay += w * hv.y; az += w * hv.z;
  }
  float4 v = make_float4(scale * ax, scale * ay, scale * az, 0.f);
  if (prev) {
    float4 pv = prev[r];
    v.x -= pv.x; v.y -= pv.y; v.z -= pv.z;
  }
  y[r] = v;
  uint2 sp = make_uint2(f2h(v.x) | ((unsigned)f2h(v.y) << 16), (unsigned)f2h(v.z));
  *(uint2*)(yh + (size_t)r * 32 + kslot * 4) = sp;
}

__device__ __forceinline__ void prop128h_row(
    const int* __restrict__ off, const int2* __restrict__ pairs,
    const ushort* __restrict__ hh, float* __restrict__ y, ushort* __restrict__ yh,
    const float* __restrict__ prev, float scale, int r, int l) {
  int s = off[r], e = off[r + 1];
  const uint2* h2 = (const uint2*)hh;
  float ax = 0.f, ay = 0.f, az = 0.f, aw = 0.f;
  int j = s;
  for (; j + 4 <= e; j += 4) {
    int2 p0 = pairs[j], p1 = pairs[j + 1], p2 = pairs[j + 2], p3 = pairs[j + 3];
    uint2 v0 = h2[(size_t)p0.x * 32 + l];
    uint2 v1 = h2[(size_t)p1.x * 32 + l];
    uint2 v2 = h2[(size_t)p2.x * 32 + l];
    uint2 v3 = h2[(size_t)p3.x * 32 + l];
    float w0 = __int_as_float(p0.y), w1 = __int_as_float(p1.y);
    float w2 = __int_as_float(p2.y), w3 = __int_as_float(p3.y);
    ax += w0 * h2f(v0.x & 0xFFFFu) + w1 * h2f(v1.x & 0xFFFFu)
        + w2 * h2f(v2.x & 0xFFFFu) + w3 * h2f(v3.x & 0xFFFFu);
    ay += w0 * h2f(v0.x >> 16) + w1 * h2f(v1.x >> 16)
        + w2 * h2f(v2.x >> 16) + w3 * h2f(v3.x >> 16);
    az += w0 * h2f(v0.y & 0xFFFFu) + w1 * h2f(v1.y & 0xFFFFu)
        + w2 * h2f(v2.y & 0xFFFFu) + w3 * h2f(v3.y & 0xFFFFu);
    aw += w0 * h2f(v0.y >> 16) + w1 * h2f(v1.y >> 16)
        + w2 * h2f(v2.y >> 16) + w3 * h2f(v3.y >> 16);
  }
  for (; j < e; ++j) {
    int2 p = pairs[j];
    uint2 v0 = h2[(size_t)p.x * 32 + l];
    float w = __int_as_float(p.y);
    ax += w * h2f(v0.x & 0xFFFFu);
    ay += w * h2f(v0.x >> 16);
    az += w * h2f(v0.y & 0xFFFFu);
    aw += w * h2f(v0.y >> 16);
  }
  float4 v = make_float4(scale * ax, scale * ay, scale * az, scale * aw);
  if (prev) {
    float4 pv = ((const float4*)prev)[(size_t)r * 32 + l];
    v.x -= pv.x; v.y -= pv.y; v.z -= pv.z; v.w -= pv.w;
  }
  if (y) ((float4*)y)[(size_t)r * 32 + l] = v;
  uint2 sp = make_uint2(f2h(v.x) | ((unsigned)f2h(v.y) << 16),
                        f2h(v.z) | ((unsigned)f2h(v.w) << 16));
  ((uint2*)yh)[(size_t)r * 32 + l] = sp;
}

// ---------------- cooperative kernel 1: prep + CSR build ----------------
struct BuildArgs {
  const float *x, *W0, *W1, *W2, *linb;
  const int *dst0, *dst1, *dst2, *D0r, *D1r;
  const int *src0, *src1, *src2, *D0c, *D1c;
  const float *D0v, *D1v;
  int *degcnt, *cntCB, *bucketTot, *bucketBase;
  float *dinv;
  int2 *scatPairs, *csrPairs;
  int *offArr;
  ushort *W0h, *Wt1, *Wt2;
  float4 *Tb0;
  ushort *Ah0;
  float *out;
};

__global__ __launch_bounds__(256) void coop_build(BuildArgs A) {
  __shared__ int lds[768];
  cg::grid_group grid = cg::this_grid();
  const int tid = threadIdx.x;
  const int gstride = gridDim.x * 256;

  // -------- phase 0: prep (fp16 weights, degcnt zero, copyx, out init) ----
  for (int i = blockIdx.x * 256 + tid; i < PREP_ALL_TOTAL; i += gstride) {
    if (i < 768 * 128) {
      int k = i / 128, n = i - k * 128;
      A.Wt1[(size_t)n * 768 + k] = f2h(A.W1[i]);
    } else if (i < 768 * 128 + 768 * 256) {
      int i2 = i - 768 * 128;
      int k = i2 / 256, n = i2 - k * 256;
      A.Wt2[(size_t)n * 768 + k] = f2h(A.W2[i2]);
    } else if (i < WPREP_TOTAL) {
      int i3 = i - 768 * 128 - 768 * 256;
      int col = i3 >> 5, k = i3 & 31;
      int a = k >> 2, jj = k & 3;
      float v = (k < 24 && jj < 3) ? A.W0[(a * 3 + jj) * 128 + col] : 0.f;
      A.W0h[(size_t)col * 32 + k] = f2h(v);
    } else if (i < WPREP_TOTAL + DEG_TOTAL) {
      A.degcnt[i - WPREP_TOTAL] = 0;
    } else if (i < WPREP_TOTAL + DEG_TOTAL + cN0) {
      int r = i - (WPREP_TOTAL + DEG_TOTAL);
      float x0 = A.x[3 * r], x1 = A.x[3 * r + 1], x2 = A.x[3 * r + 2];
      A.Tb0[r] = make_float4(x0, x1, x2, 0.f);
      uint4 z = make_uint4(0, 0, 0, 0);
      uint4 first = make_uint4(f2h(x0) | ((unsigned)f2h(x1) << 16),
                               (unsigned)f2h(x2), 0, 0);
      uint4* p = (uint4*)(A.Ah0 + (size_t)r * 32);
      p[0] = first; p[1] = z; p[2] = z; p[3] = z;
    } else {
      int o = i - (WPREP_TOTAL + DEG_TOTAL + cN0);
      A.out[o] = A.linb[o];
    }
  }
  grid.sync();

  // -------- phase 1: c1 count (chunk x bucket histogram + degree) --------
  if (blockIdx.x < TCB) {
    int cb = blockIdx.x;
    int j = job_of_cb(cb);
    int lb = cb - JCBASE[j];
    const int* keys;
    const int* srck = nullptr;
    int dbase = 0;
    switch (j) {
      case 0: keys = A.dst0; srck = A.src0; dbase = DEGBASE[0]; break;
      case 1: keys = A.dst1; srck = A.src1; dbase = DEGBASE[1]; break;
      case 2: keys = A.dst2; srck = A.src2; dbase = DEGBASE[2]; break;
      case 3: keys = A.D0r; break;
      default: keys = A.D1r; break;
    }
    int nB = JB[j];
    for (int b = tid; b < nB; b += 256) lds[b] = 0;
    __syncthreads();
    int e0 = lb * CHUNK;
    int e1 = min(e0 + CHUNK, JE[j]);
    for (int e = e0 + tid; e < e1; e += 256) {
      atomicAdd(&lds[keys[e] >> 8], 1);
      if (srck) atomicAdd(&A.degcnt[dbase + srck[e]], 1);
    }
    __syncthreads();
    for (int b = tid; b < nB; b += 256)
      A.cntCB[cb * BSTRIDE + b] = lds[b];
  }
  grid.sync();

  // -------- phase 2: c2a per-bucket chunk scan + dinv finalize -----------
  {
    int* s = lds;
    int g = blockIdx.x;          // grid == TB exactly
    int j = job_of_bucket(g);
    int b = g - JBBASE[j];
    int cb0 = JCBASE[j], nCB = JCB[j];
    int carry = 0;
    for (int c0 = 0; c0 < nCB; c0 += 256) {
      int i = c0 + tid;
      int v = (i < nCB) ? A.cntCB[(cb0 + i) * BSTRIDE + b] : 0;
      s[tid] = v;
      __syncthreads();
      for (int d = 1; d < 256; d <<= 1) {
        int t = (tid >= d) ? s[tid - d] : 0;
        __syncthreads();
        s[tid] += t;
        __syncthreads();
      }
      if (i < nCB) A.cntCB[(cb0 + i) * BSTRIDE + b] = carry + s[tid] - v;
      carry += s[255];
      __syncthreads();
    }
    if (tid == 0) A.bucketTot[g] = carry;
    int idx = blockIdx.x * 256 + tid;
    if (idx < DEG_TOTAL) {
      int c = A.degcnt[idx];
      A.dinv[idx] = (c > 0) ? rsqrtf((float)c) : 0.f;
    }
  }
  grid.sync();

  // -------- phase 3: c2b per-job bucket scan ----------------------------
  if (blockIdx.x < 5) {
    int* s = lds;
    int j = blockIdx.x;
    int g0 = JBBASE[j], nB = JB[j];
    int carry = 0;
    for (int c0 = 0; c0 < nB; c0 += 256) {
      int i = c0 + tid;
      int v = (i < nB) ? A.bucketTot[g0 + i] : 0;
      s[tid] = v;
      __syncthreads();
      for (int d = 1; d < 256; d <<= 1) {
        int t = (tid >= d) ? s[tid - d] : 0;
        __syncthreads();
        s[tid] += t;
        __syncthreads();
      }
      if (i < nB) A.bucketBase[g0 + i] = carry + s[tid] - v;
      carry += s[255];
      __syncthreads();
    }
  }
  grid.sync();

  // -------- phase 4: c3 scatter into bucket-chunk regions ---------------
  if (blockIdx.x < TCB) {
    int* base = lds;
    int cb = blockIdx.x;
    int j = job_of_cb(cb);
    int lb = cb - JCBASE[j];
    const int* dk; const int* sk; const float* vv = nullptr;
    switch (j) {
      case 0: dk = A.dst0; sk = A.src0; break;
      case 1: dk = A.dst1; sk = A.src1; break;
      case 2: dk = A.dst2; sk = A.src2; break;
      case 3: dk = A.D0r; sk = A.D0c; vv = A.D0v; break;
      default: dk = A.D1r; sk = A.D1c; vv = A.D1v; break;
    }
    int nB = JB[j];
    for (int b = tid; b < nB; b += 256)
      base[b] = EBASE[j] + A.bucketBase[JBBASE[j] + b] + A.cntCB[cb * BSTRIDE + b];
    __syncthreads();
    int e0 = lb * CHUNK;
    int e1 = min(e0 + CHUNK, JE[j]);
    for (int e = e0 + tid; e < e1; e += 256) {
      int d = dk[e];
      int s = sk[e];
      float w;
      if (j < 3) w = -(A.dinv[DEGBASE[j] + s] * A.dinv[DEGBASE[j] + d]);
      else w = vv[e];
      int pos = atomicAdd(&base[d >> 8], 1);
      A.scatPairs[pos] = make_int2(((d & 255) << 17) | s, __float_as_int(w));
    }
  }
  grid.sync();

  // -------- phase 5: dcsr per-bucket node sort -> final CSR -------------
  {
    int* cnt  = lds;
    int* sArr = lds + 256;
    int* cur  = lds + 512;
    int g = blockIdx.x;          // grid == TB exactly
    int j = job_of_bucket(g);
    int b = g - JBBASE[j];
    int relBase = A.bucketBase[g];
    int st = EBASE[j] + relBase;
    int en = st + A.bucketTot[g];
    cnt[tid] = 0;
    __syncthreads();
    for (int idx = st + tid; idx < en; idx += 256)
      atomicAdd(&cnt[A.scatPairs[idx].x >> 17], 1);
    __syncthreads();
    int v = cnt[tid];
    sArr[tid] = v;
    __syncthreads();
    for (int d = 1; d < 256; d <<= 1) {
      int t = (tid >= d) ? sArr[tid - d] : 0;
      __syncthreads();
      sArr[tid] += t;
      __syncthreads();
    }
    int excl = sArr[tid] - v;
    int node = b * 256 + tid;
    if (node < JN[j]) A.offArr[NBASE[j] + node] = relBase + excl;
    if (tid == 0 && b == JB[j] - 1) A.offArr[NBASE[j] + JN[j]] = JE[j];
    cur[tid] = st + excl;
    __syncthreads();
    for (int idx = st + tid; idx < en; idx += 256) {
      int2 p = A.scatPairs[idx];
      int dl = p.x >> 17;
      int s = p.x & 0x1FFFF;
      int pos = atomicAdd(&cur[dl], 1);
      A.csrPairs[pos] = make_int2(s, p.y);
    }
  }
}

// ---------------- cooperative kernel 2: level-0 Chebyshev x5 -------------
struct L0Args {
  const int* off;
  const int2* pairs;
  float4* Tb0;
  ushort* Ah0;
};

__global__ __launch_bounds__(256) void coop_prop0(L0Args A) {
  cg::grid_group grid = cg::this_grid();
  const int r = blockIdx.x * 256 + threadIdx.x;
  float4* T0 = A.Tb0;
  float4* T1 = A.Tb0 + (size_t)1 * cN0;
  float4* T2 = A.Tb0 + (size_t)2 * cN0;
  float4* T3 = A.Tb0 + (size_t)3 * cN0;
  float4* T4 = A.Tb0 + (size_t)4 * cN0;
  float4* T5 = A.Tb0 + (size_t)5 * cN0;
  if (r < cN0) prop3_row(A.off, A.pairs, T0, T1, nullptr, 1.f, A.Ah0, 1, r);
  grid.sync();
  if (r < cN0) prop3_row(A.off, A.pairs, T1, T2, T0, 2.f, A.Ah0, 2, r);
  grid.sync();
  if (r < cN0) prop3_row(A.off, A.pairs, T2, T3, T1, 2.f, A.Ah0, 3, r);
  grid.sync();
  if (r < cN0) prop3_row(A.off, A.pairs, T3, T4, T2, 2.f, A.Ah0, 4, r);
  grid.sync();
  if (r < cN0) prop3_row(A.off, A.pairs, T4, T5, T3, 2.f, A.Ah0, 5, r);
}

// ------------- cooperative kernel 3/4: pool + 5 prop steps ---------------
struct LvArgs {
  const int* offP;           // pool CSR
  const int2* pairsP;
  const ushort* hin;         // pooled fp16 input rows
  const int* off;            // conv CSR
  const int2* pairs;
  float* Tl;                 // fp32 slabs [6][N][128]
  ushort* Th;                // fp16 slabs [6][N][128]
  int N;
};

__global__ __launch_bounds__(256) void coop_pool_prop(LvArgs A) {
  cg::grid_group grid = cg::this_grid();
  const int sub = threadIdx.x >> 5, l = threadIdx.x & 31;
  const int N = A.N;
  const int NG = (N + 7) / 8;
  const size_t slab = (size_t)N * 128;

  // pool: gather fp16 h -> T(0) fp32 + Th(0) fp16
  for (int gg = blockIdx.x; gg < NG; gg += gridDim.x) {
    int r = gg * 8 + sub;
    if (r < N)
      prop128h_row(A.offP, A.pairsP, A.hin, A.Tl, A.Th, nullptr, 1.f, r, l);
  }
  grid.sync();
  // Chebyshev steps 1..5 on conv CSR
  for (int s = 1; s <= 5; ++s) {
    const ushort* hin = A.Th + (size_t)(s - 1) * slab;
    float* y = (s < 5) ? (A.Tl + (size_t)s * slab) : nullptr;
    ushort* yh = A.Th + (size_t)s * slab;
    const float* prev = (s >= 2) ? (A.Tl + (size_t)(s - 2) * slab) : nullptr;
    float scale = (s == 1) ? 1.f : 2.f;
    for (int gg = blockIdx.x; gg < NG; gg += gridDim.x) {
      int r = gg * 8 + sub;
      if (r < N)
        prop128h_row(A.off, A.pairs, hin, y, yh, prev, scale, r, l);
    }
    if (s < 5) grid.sync();
  }
}

// ---------------- h0 MFMA (standalone, unchanged) ------------------------
__global__ __launch_bounds__(256, 2) void h0_mfma_kernel(
    const ushort* __restrict__ Ah, const ushort* __restrict__ W0h,
    const float* __restrict__ b0, ushort* __restrict__ h0h, int M) {
  __shared__ ushort Al[64][40];
  __shared__ ushort Bl[128][40];
  __shared__ ushort Hs[64][128];
  const int tid = threadIdx.x;
  const int rowBase = blockIdx.x * 64;
  const int wave = tid >> 6;
  const int lane = tid & 63;
  const int m16 = lane & 15;
  const int quad = lane >> 4;
  {
    int sRow = tid >> 2;
    int sK8 = (tid & 3) * 8;
    int row = rowBase + sRow;
    uint4 av = make_uint4(0, 0, 0, 0);
    if (row < M) av = *(const uint4*)(Ah + (size_t)row * 32 + sK8);
    *(uint4*)&Al[sRow][sK8] = av;
  }
#pragma unroll
  for (int l = 0; l < 2; ++l) {
    int lin = tid + l * 256;
    int bRow = lin >> 2;
    int bK8 = (lin & 3) * 8;
    *(uint4*)&Bl[bRow][bK8] = *(const uint4*)(W0h + (size_t)bRow * 32 + bK8);
  }
  __syncthreads();
  short8 a = *(const short8*)&Al[wave * 16 + m16][quad * 8];
  floatx4 acc[8];
#pragma unroll
  for (int c = 0; c < 8; ++c) {
    floatx4 z;
    z[0] = 0.f; z[1] = 0.f; z[2] = 0.f; z[3] = 0.f;
    short8 b = *(const short8*)&Bl[c * 16 + m16][quad * 8];
    acc[c] = __builtin_amdgcn_mfma_f32_16x16x32_f16(a, b, z, 0, 0, 0);
  }
#pragma unroll
  for (int c = 0; c < 8; ++c) {
    int col = c * 16 + m16;
    float bv = b0[col];
#pragma unroll
    for (int r = 0; r < 4; ++r)
      Hs[wave * 16 + quad * 4 + r][col] = f2h(fmaxf(acc[c][r] + bv, 0.f));
  }
  __syncthreads();
  const uint4* ls = (const uint4*)&Hs[0][0];
  uint4* gd = (uint4*)(h0h + (size_t)rowBase * 128);
#pragma unroll
  for (int i = 0; i < 4; ++i) {
    int idx = tid + i * 256;
    if (rowBase + (idx >> 4) < M) gd[idx] = ls[idx];
  }
}

// ---------------- main GEMM (fp16 A/B; optional fp16-only output) --------
template <int RELU, int OUTH>
__global__ __launch_bounds__(256, 2) void gemm_mfma_kernel(
    const ushort* __restrict__ Th, const ushort* __restrict__ Wt,
    const float* __restrict__ bias, float* __restrict__ C, ushort* __restrict__ Ch,
    int M, int N) {
  __shared__ ushort Al[64][40];
  __shared__ ushort Bl[128][40];
  __shared__ ushort Hs[64][128];
  const int tid = threadIdx.x;
  const int rowBase = blockIdx.x * 64;
  const int colBase = blockIdx.y * 128;
  const int wave = tid >> 6;
  const int lane = tid & 63;
  const int m16 = lane & 15;
  const int quad = lane >> 4;
  const size_t Mstride = (size_t)M * 128;

  floatx4 acc[8];
#pragma unroll
  for (int c = 0; c < 8; ++c)
#pragma unroll
    for (int r = 0; r < 4; ++r) acc[c][r] = 0.f;

  const int sRow = tid >> 2;
  const int sK8 = (tid & 3) * 8;
  const int growA = rowBase + sRow;
  const bool aValid = growA < M;

  for (int kc = 0; kc < 24; ++kc) {
    uint4 av = make_uint4(0, 0, 0, 0);
    if (aValid)
      av = *(const uint4*)(Th + (size_t)(kc >> 2) * Mstride + (size_t)growA * 128
                           + ((kc & 3) << 5) + sK8);
    *(uint4*)&Al[sRow][sK8] = av;
#pragma unroll
    for (int l = 0; l < 2; ++l) {
      int lin = tid + l * 256;
      int bRow = lin >> 2;
      int bK8 = (lin & 3) * 8;
      *(uint4*)&Bl[bRow][bK8] =
          *(const uint4*)(Wt + (size_t)(colBase + bRow) * 768 + kc * 32 + bK8);
    }
    __syncthreads();

    short8 a = *(const short8*)&Al[wave * 16 + m16][quad * 8];
#pragma unroll
    for (int c = 0; c < 8; ++c) {
      short8 b = *(const short8*)&Bl[c * 16 + m16][quad * 8];
      acc[c] = __builtin_amdgcn_mfma_f32_16x16x32_f16(a, b, acc[c], 0, 0, 0);
    }
    __syncthreads();
  }

  if (OUTH) {
#pragma unroll
    for (int c = 0; c < 8; ++c) {
      int col = c * 16 + m16;
      float bv = bias[col];
#pragma unroll
      for (int r = 0; r < 4; ++r) {
        float v = acc[c][r] + bv;
        if (RELU) v = fmaxf(v, 0.f);
        Hs[wave * 16 + quad * 4 + r][col] = f2h(v);
      }
    }
    __syncthreads();
    const uint4* ls = (const uint4*)&Hs[0][0];
    uint4* gd = (uint4*)(Ch + (size_t)rowBase * 128);
#pragma unroll
    for (int i = 0; i < 4; ++i) {
      int idx = tid + i * 256;
      if (rowBase + (idx >> 4) < M) gd[idx] = ls[idx];
    }
  } else {
#pragma unroll
    for (int c = 0; c < 8; ++c) {
      int col = colBase + c * 16 + m16;
      float bv = bias[col];
#pragma unroll
      for (int r = 0; r < 4; ++r) {
        int row = rowBase + wave * 16 + quad * 4 + r;
        if (row < M) {
          float v = acc[c][r] + bv;
          if (RELU) v = fmaxf(v, 0.f);
          C[(size_t)row * N + col] = v;
        }
      }
    }
  }
}

// ---------------- linear head ----------------
__global__ __launch_bounds__(256) void linear_kernel(const float* __restrict__ Wl,
                                                     const float* __restrict__ h,
                                                     float* __restrict__ out, int D) {
  float p[10];
#pragma unroll
  for (int j = 0; j < 10; ++j) p[j] = 0.f;
  int stride = gridDim.x * blockDim.x;
  for (int i = blockIdx.x * blockDim.x + threadIdx.x; i < D; i += stride) {
    float hv = h[i];
#pragma unroll
    for (int j = 0; j < 10; ++j) p[j] += Wl[(size_t)j * D + i] * hv;
  }
#pragma unroll
  for (int j = 0; j < 10; ++j) {
#pragma unroll
    for (int off = 32; off > 0; off >>= 1) p[j] += __shfl_down(p[j], off, 64);
  }
  __shared__ float s[4][10];
  int wave = threadIdx.x >> 6, lane = threadIdx.x & 63;
  if (lane == 0) {
#pragma unroll
    for (int j = 0; j < 10; ++j) s[wave][j] = p[j];
  }
  __syncthreads();
  if (threadIdx.x < 10) {
    float t = s[0][threadIdx.x] + s[1][threadIdx.x] + s[2][threadIdx.x] + s[3][threadIdx.x];
    atomicAdd(&out[threadIdx.x], t);
  }
}

// ---------------- host orchestration ----------------
extern "C" void kernel_launch(void* const* d_in, const int* in_sizes, int n_in,
                              void* d_out, int out_size, void* d_ws, size_t ws_size,
                              hipStream_t stream) {
  const float* x    = (const float*)d_in[0];
  const int*   ei0  = (const int*)d_in[1];
  const int*   ei1  = (const int*)d_in[2];
  const int*   ei2  = (const int*)d_in[3];
  const float* W0   = (const float*)d_in[4];
  const float* b0   = (const float*)d_in[5];
  const float* W1   = (const float*)d_in[6];
  const float* b1   = (const float*)d_in[7];
  const float* W2   = (const float*)d_in[8];
  const float* b2   = (const float*)d_in[9];
  const int*   D0r  = (const int*)d_in[10];
  const int*   D0c  = (const int*)d_in[11];
  const float* D0v  = (const float*)d_in[12];
  const int*   D1r  = (const int*)d_in[13];
  const int*   D1c  = (const int*)d_in[14];
  const float* D1v  = (const float*)d_in[15];
  const float* linW = (const float*)d_in[16];
  const float* linb = (const float*)d_in[17];
  float* out = (float*)d_out;
  (void)in_sizes; (void)n_in; (void)out_size; (void)ws_size;

  const int* src0 = ei0;            const int* dst0 = ei0 + cE0;
  const int* src1 = ei1;            const int* dst1 = ei1 + cE1;
  const int* src2 = ei2;            const int* dst2 = ei2 + cE2;

  float* ws = (float*)d_ws;
  size_t off = 0;
  auto alloc = [&](size_t n) {
    float* p = ws + off;
    off += (n + 63) & ~size_t(63);
    return p;
  };
  float* dinv       = alloc(DEG_TOTAL);
  int*   degcnt     = (int*)alloc(DEG_TOTAL);
  int*   cntCB      = (int*)alloc((size_t)TCB * BSTRIDE);
  int*   bucketTot  = (int*)alloc(TB);
  int*   bucketBase = (int*)alloc(TB);
  int2*  scatPairs  = (int2*)alloc((size_t)2 * E_TOTAL);
  int2*  csrPairs   = (int2*)alloc((size_t)2 * E_TOTAL);
  int*   offArr     = (int*)alloc(NPAD_TOTAL);
  ushort* W0h       = (ushort*)alloc(128 * 32 / 2);
  ushort* Wt1       = (ushort*)alloc(768 * 128 / 2);
  ushort* Wt2       = (ushort*)alloc(768 * 256 / 2);
  float4* Tb0       = (float4*)alloc((size_t)6 * cN0 * 4);
  ushort* Ah0       = (ushort*)alloc((size_t)cN0 * 16);
  ushort* h0h       = (ushort*)alloc((size_t)cN0 * 64);
  float* Tlvl1      = alloc((size_t)6 * cN1 * 128);
  ushort* Th1       = (ushort*)alloc((size_t)6 * cN1 * 64);
  ushort* out1h     = (ushort*)alloc((size_t)cN1 * 64);
  float* Tlvl2      = alloc((size_t)6 * cN2 * 128);
  ushort* Th2       = (ushort*)alloc((size_t)6 * cN2 * 64);
  float* out2       = alloc((size_t)cN2 * 256);

  auto seg_off   = [&](int s) { return offArr + NBASE[s]; };
  auto seg_pairs = [&](int s) { return csrPairs + EBASE[s]; };

  // ---- K1: prep + CSR build (cooperative, 6 phases) ----
  BuildArgs BA;
  BA.x = x; BA.W0 = W0; BA.W1 = W1; BA.W2 = W2; BA.linb = linb;
  BA.dst0 = dst0; BA.dst1 = dst1; BA.dst2 = dst2; BA.D0r = D0r; BA.D1r = D1r;
  BA.src0 = src0; BA.src1 = src1; BA.src2 = src2; BA.D0c = D0c; BA.D1c = D1c;
  BA.D0v = D0v; BA.D1v = D1v;
  BA.degcnt = degcnt; BA.cntCB = cntCB; BA.bucketTot = bucketTot;
  BA.bucketBase = bucketBase; BA.dinv = dinv;
  BA.scatPairs = scatPairs; BA.csrPairs = csrPairs; BA.offArr = offArr;
  BA.W0h = W0h; BA.Wt1 = Wt1; BA.Wt2 = Wt2;
  BA.Tb0 = Tb0; BA.Ah0 = Ah0; BA.out = out;
  {
    void* args[] = { &BA };
    hipLaunchCooperativeKernel((void*)coop_build, dim3(TB), dim3(256),
                               args, 0, stream);
  }

  // ---- K2: level-0 Chebyshev x5 (cooperative) ----
  L0Args L0;
  L0.off = seg_off(0); L0.pairs = seg_pairs(0); L0.Tb0 = Tb0; L0.Ah0 = Ah0;
  {
    void* args[] = { &L0 };
    hipLaunchCooperativeKernel((void*)coop_prop0, dim3((cN0 + 255) / 256),
                               dim3(256), args, 0, stream);
  }

  // ---- h0 MFMA ----
  h0_mfma_kernel<<<(cN0 + 63) / 64, 256, 0, stream>>>(Ah0, W0h, b0, h0h, cN0);

  // ---- K3: pool0 + level-1 Chebyshev x5 (cooperative) ----
  LvArgs L1;
  L1.offP = seg_off(3); L1.pairsP = seg_pairs(3); L1.hin = h0h;
  L1.off = seg_off(1); L1.pairs = seg_pairs(1);
  L1.Tl = Tlvl1; L1.Th = Th1; L1.N = cN1;
  {
    void* args[] = { &L1 };
    hipLaunchCooperativeKernel((void*)coop_pool_prop, dim3(512), dim3(256),
                               args, 0, stream);
  }

  // ---- gemm1 ----
  {
    dim3 g((cN1 + 63) / 64, 1);
    gemm_mfma_kernel<1, 1><<<g, 256, 0, stream>>>(Th1, Wt1, b1, nullptr, out1h,
                                                  cN1, 128);
  }

  // ---- K4: pool1 + level-2 Chebyshev x5 (cooperative) ----
  LvArgs L2;
  L2.offP = seg_off(4); L2.pairsP = seg_pairs(4); L2.hin = out1h;
  L2.off = seg_off(2); L2.pairs = seg_pairs(2);
  L2.Tl = Tlvl2; L2.Th = Th2; L2.N = cN2;
  {
    void* args[] = { &L2 };
    hipLaunchCooperativeKernel((void*)coop_pool_prop, dim3(512), dim3(256),
                               args, 0, stream);
  }

  // ---- gemm2 ----
  {
    dim3 g((cN2 + 63) / 64, 2);
    gemm_mfma_kernel<0, 0><<<g, 256, 0, stream>>>(Th2, Wt2, b2, out2, nullptr,
                                                  cN2, 256);
  }

  // ---- linear head (out pre-initialized with linb in K1 phase 0) ----
  linear_kernel<<<512, 256, 0, stream>>>(linW, out2, out, cD);
}

// Round 5
// 482.918 us; speedup vs baseline: 3.5290x; 3.5290x over previous
//
#include <hip/hip_runtime.h>

// ChebClassifier R14: revert R13 coop (grid.sync pathological: 473us build).
// Base = R12 (fp16 side-channel, 418.8us) +
// (a) direct CSR build: c1 global-atomic node counts -> 2-level scan
//     (S1/S2/S3) -> single direct scatter via per-node cursors.
//     Drops dcsr, scatPairs, cntCB (was ~8x write-amplified double scatter,
//     290K LDS bank conflicts).
// (b) csr_prop3 level-0: 4 lanes/row + quad shuffle reduce (391 -> 1563
//     blocks; was 1.5 waves/SIMD latency-bound).

namespace {
constexpr int cN0 = 100000, cN1 = 25000, cN2 = 6250;
constexpr int cE0 = 600000, cE1 = 150000, cE2 = 37500;
constexpr int cD  = cN2 * 256;

// jobs 0-4: dst-keyed CSR builds (conv0, conv1, conv2, pool0, pool1)
constexpr int JN[5]  = {cN0, cN1, cN2, cN1, cN2};
constexpr int JE[5]  = {cE0, cE1, cE2, 100000, 25000};
constexpr int JB[5]  = {391, 98, 25, 98, 25};        // 256-node groups
constexpr int JBBASE[6] = {0, 391, 489, 514, 612, 637};
constexpr int TB = 637;
constexpr int JCB[5] = {293, 74, 19, 49, 13};        // 2048-edge chunks
constexpr int JCBASE[6] = {0, 293, 367, 386, 435, 448};
constexpr int TCB = 448;
constexpr int CHUNK = 2048;

constexpr int EBASE[5]   = {0, 600000, 750000, 787500, 887500};
constexpr int E_TOTAL    = 912500;
constexpr int NBASE[5]   = {0, 100096, 125184, 131584, 156672};
constexpr int NPAD_TOTAL = 163072;
constexpr int DEGBASE[3] = {0, 100000, 125000};
constexpr int DEG_TOTAL  = 131250;
constexpr int WPREP_TOTAL = 768 * 128 + 768 * 256 + 128 * 32;
constexpr int PREP_ALL_TOTAL = WPREP_TOTAL + DEG_TOTAL + NPAD_TOTAL + cN0 + 10;
}

typedef __attribute__((ext_vector_type(8))) short short8;
typedef __attribute__((ext_vector_type(4))) float floatx4;

__device__ inline ushort f2h(float f) {
  union { _Float16 h; ushort u; } v;
  v.h = (_Float16)f;
  return v.u;
}
__device__ inline float h2f(unsigned lo16) {
  union { ushort u; _Float16 h; } v;
  v.u = (ushort)lo16;
  return (float)v.h;
}

__device__ inline int job_of_cb(int cb) {
  int j = 0;
  while (cb >= JCBASE[j + 1]) ++j;
  return j;
}
__device__ inline int job_of_bucket(int g) {
  int j = 0;
  while (g >= JBBASE[j + 1]) ++j;
  return j;
}

// ---------------- direct CSR build ----------------
// c1: per-dst node counts (CSR) + per-src degree (dinv), global atomics
__global__ __launch_bounds__(256) void c1_count_kernel(
    const int* __restrict__ k0, const int* __restrict__ k1, const int* __restrict__ k2,
    const int* __restrict__ k3, const int* __restrict__ k4,
    const int* __restrict__ s0, const int* __restrict__ s1, const int* __restrict__ s2,
    int* __restrict__ degcnt, int* __restrict__ nodecnt) {
  int cb = blockIdx.x;
  int j = job_of_cb(cb);
  int lb = cb - JCBASE[j];
  const int* keys;
  const int* srck = nullptr;
  int dbase = 0;
  switch (j) {
    case 0: keys = k0; srck = s0; dbase = DEGBASE[0]; break;
    case 1: keys = k1; srck = s1; dbase = DEGBASE[1]; break;
    case 2: keys = k2; srck = s2; dbase = DEGBASE[2]; break;
    case 3: keys = k3; break;
    default: keys = k4; break;
  }
  int nb = NBASE[j];
  int e0 = lb * CHUNK;
  int e1 = min(e0 + CHUNK, JE[j]);
  for (int e = e0 + threadIdx.x; e < e1; e += 256) {
    atomicAdd(&nodecnt[nb + keys[e]], 1);
    if (srck) atomicAdd(&degcnt[dbase + srck[e]], 1);
  }
}

// S1: per-256-node-group exclusive scan of nodecnt -> offArr(partial),
// group totals -> blockTot; fused dinv finalize.
__global__ __launch_bounds__(256) void s1_scan_kernel(
    const int* __restrict__ nodecnt, int* __restrict__ offArr,
    int* __restrict__ blockTot,
    const int* __restrict__ degcnt, float* __restrict__ dinv) {
  __shared__ int s[256];
  int g = blockIdx.x;                 // grid == TB
  int j = job_of_bucket(g);
  int b = g - JBBASE[j];
  int idx = NBASE[j] + b * 256 + threadIdx.x;
  int v = nodecnt[idx];               // padding nodes are zero
  s[threadIdx.x] = v;
  __syncthreads();
  for (int d = 1; d < 256; d <<= 1) {
    int t = (threadIdx.x >= d) ? s[threadIdx.x - d] : 0;
    __syncthreads();
    s[threadIdx.x] += t;
    __syncthreads();
  }
  offArr[idx] = s[threadIdx.x] - v;   // exclusive, pre-base
  if (threadIdx.x == 0) blockTot[g] = s[255];
  // fused dinv finalize (degcnt complete after c1)
  int di = blockIdx.x * 256 + threadIdx.x;
  if (di < DEG_TOTAL) {
    int c = degcnt[di];
    dinv[di] = (c > 0) ? rsqrtf((float)c) : 0.f;
  }
}

// S2: per-job scan of group totals -> blockBase
__global__ __launch_bounds__(256) void s2_scan_kernel(const int* __restrict__ blockTot,
                                                      int* __restrict__ blockBase) {
  __shared__ int s[256];
  int j = blockIdx.x;
  int g0 = JBBASE[j], nB = JB[j];
  int carry = 0;
  for (int c0 = 0; c0 < nB; c0 += 256) {
    int i = c0 + threadIdx.x;
    int v = (i < nB) ? blockTot[g0 + i] : 0;
    s[threadIdx.x] = v;
    __syncthreads();
    for (int d = 1; d < 256; d <<= 1) {
      int t = (threadIdx.x >= d) ? s[threadIdx.x - d] : 0;
      __syncthreads();
      s[threadIdx.x] += t;
      __syncthreads();
    }
    if (i < nB) blockBase[g0 + i] = carry + s[threadIdx.x] - v;
    carry += s[255];
    __syncthreads();
  }
}

// S3: offArr += blockBase; cursor = offArr; write sentinel off[N] = E
__global__ __launch_bounds__(256) void s3_fix_kernel(int* __restrict__ offArr,
                                                     int* __restrict__ cursor,
                                                     const int* __restrict__ blockBase) {
  int g = blockIdx.x;                 // grid == TB
  int j = job_of_bucket(g);
  int b = g - JBBASE[j];
  int idx = NBASE[j] + b * 256 + threadIdx.x;
  int v = offArr[idx] + blockBase[g];
  offArr[idx] = v;
  cursor[idx] = v;
  if (threadIdx.x == 0 && b == JB[j] - 1) offArr[NBASE[j] + JN[j]] = JE[j];
}

// scatter: one pass over edges -> final CSR slot via per-node cursor
__global__ __launch_bounds__(256) void scatter_kernel(
    const int* __restrict__ d0, const int* __restrict__ s0,
    const int* __restrict__ d1, const int* __restrict__ s1,
    const int* __restrict__ d2, const int* __restrict__ s2,
    const int* __restrict__ p0r, const int* __restrict__ p0c, const float* __restrict__ p0v,
    const int* __restrict__ p1r, const int* __restrict__ p1c, const float* __restrict__ p1v,
    const float* __restrict__ dinv,
    int* __restrict__ cursor, int2* __restrict__ csrPairs) {
  int cb = blockIdx.x;
  int j = job_of_cb(cb);
  int lb = cb - JCBASE[j];
  const int* dk; const int* sk; const float* vv = nullptr;
  switch (j) {
    case 0: dk = d0; sk = s0; break;
    case 1: dk = d1; sk = s1; break;
    case 2: dk = d2; sk = s2; break;
    case 3: dk = p0r; sk = p0c; vv = p0v; break;
    default: dk = p1r; sk = p1c; vv = p1v; break;
  }
  int nb = NBASE[j];
  int eb = EBASE[j];
  int e0 = lb * CHUNK;
  int e1 = min(e0 + CHUNK, JE[j]);
  for (int e = e0 + threadIdx.x; e < e1; e += 256) {
    int d = dk[e];
    int s = sk[e];
    float w;
    if (j < 3) w = -(dinv[DEGBASE[j] + s] * dinv[DEGBASE[j] + d]);
    else w = vv[e];
    int pos = atomicAdd(&cursor[nb + d], 1);
    csrPairs[eb + pos] = make_int2(s, __float_as_int(w));
  }
}

// ---------------- unified prop/pool over 128-wide rows ----------------
__global__ __launch_bounds__(256) void csr_prop128h_kernel(
    const int* __restrict__ off, const int2* __restrict__ pairs,
    const ushort* __restrict__ hh, float* __restrict__ y, ushort* __restrict__ yh,
    const float* __restrict__ prev, float scale, int N) {
  int r = blockIdx.x * 8 + (threadIdx.x >> 5);
  int l = threadIdx.x & 31;
  if (r >= N) return;
  int s = off[r], e = off[r + 1];
  const uint2* h2 = (const uint2*)hh;
  float ax = 0.f, ay = 0.f, az = 0.f, aw = 0.f;
  int j = s;
  for (; j + 4 <= e; j += 4) {
    int2 p0 = pairs[j], p1 = pairs[j + 1], p2 = pairs[j + 2], p3 = pairs[j + 3];
    uint2 v0 = h2[(size_t)p0.x * 32 + l];
    uint2 v1 = h2[(size_t)p1.x * 32 + l];
    uint2 v2 = h2[(size_t)p2.x * 32 + l];
    uint2 v3 = h2[(size_t)p3.x * 32 + l];
    float w0 = __int_as_float(p0.y), w1 = __int_as_float(p1.y);
    float w2 = __int_as_float(p2.y), w3 = __int_as_float(p3.y);
    ax += w0 * h2f(v0.x & 0xFFFFu) + w1 * h2f(v1.x & 0xFFFFu)
        + w2 * h2f(v2.x & 0xFFFFu) + w3 * h2f(v3.x & 0xFFFFu);
    ay += w0 * h2f(v0.x >> 16) + w1 * h2f(v1.x >> 16)
        + w2 * h2f(v2.x >> 16) + w3 * h2f(v3.x >> 16);
    az += w0 * h2f(v0.y & 0xFFFFu) + w1 * h2f(v1.y & 0xFFFFu)
        + w2 * h2f(v2.y & 0xFFFFu) + w3 * h2f(v3.y & 0xFFFFu);
    aw += w0 * h2f(v0.y >> 16) + w1 * h2f(v1.y >> 16)
        + w2 * h2f(v2.y >> 16) + w3 * h2f(v3.y >> 16);
  }
  for (; j < e; ++j) {
    int2 p = pairs[j];
    uint2 v0 = h2[(size_t)p.x * 32 + l];
    float w = __int_as_float(p.y);
    ax += w * h2f(v0.x & 0xFFFFu);
    ay += w * h2f(v0.x >> 16);
    az += w * h2f(v0.y & 0xFFFFu);
    aw += w * h2f(v0.y >> 16);
  }
  float4 v = make_float4(scale * ax, scale * ay, scale * az, scale * aw);
  if (prev) {
    float4 pv = ((const float4*)prev)[(size_t)r * 32 + l];
    v.x -= pv.x; v.y -= pv.y; v.z -= pv.z; v.w -= pv.w;
  }
  if (y) ((float4*)y)[(size_t)r * 32 + l] = v;
  uint2 sp = make_uint2(f2h(v.x) | ((unsigned)f2h(v.y) << 16),
                        f2h(v.z) | ((unsigned)f2h(v.w) << 16));
  ((uint2*)yh)[(size_t)r * 32 + l] = sp;
}

// level-0: 4 lanes per row, quad shuffle reduce; fp32 slab + fp16 slot kout
__global__ __launch_bounds__(256) void csr_prop3_kernel(
    const int* __restrict__ off, const int2* __restrict__ pairs,
    const float4* __restrict__ h, float4* __restrict__ y,
    const float4* __restrict__ prev, float scale, int N,
    ushort* __restrict__ yh, int kout) {
  int t = blockIdx.x * 256 + threadIdx.x;
  int r = t >> 2;
  int q = t & 3;
  if (r >= N) return;
  int s = off[r], e = off[r + 1];
  float ax = 0.f, ay = 0.f, az = 0.f;
  for (int j = s + q; j < e; j += 4) {
    int2 p = pairs[j];
    float4 hv = h[p.x];
    float w = __int_as_float(p.y);
    ax += w * hv.x; ay += w * hv.y; az += w * hv.z;
  }
  ax += __shfl_xor(ax, 1); ay += __shfl_xor(ay, 1); az += __shfl_xor(az, 1);
  ax += __shfl_xor(ax, 2); ay += __shfl_xor(ay, 2); az += __shfl_xor(az, 2);
  if (q == 0) {
    float4 v = make_float4(scale * ax, scale * ay, scale * az, 0.f);
    if (prev) {
      float4 pv = prev[r];
      v.x -= pv.x; v.y -= pv.y; v.z -= pv.z;
    }
    y[r] = v;
    uint2 sp = make_uint2(f2h(v.x) | ((unsigned)f2h(v.y) << 16), (unsigned)f2h(v.z));
    *(uint2*)(yh + (size_t)r * 32 + kout * 4) = sp;
  }
}

// h0 = relu(b0 + A[M,32]fp16 @ W0h[32,128]) via single-chunk MFMA; fp16 out
__global__ __launch_bounds__(256, 2) void h0_mfma_kernel(
    const ushort* __restrict__ Ah, const ushort* __restrict__ W0h,
    const float* __restrict__ b0, ushort* __restrict__ h0h, int M) {
  __shared__ ushort Al[64][40];
  __shared__ ushort Bl[128][40];
  __shared__ ushort Hs[64][128];
  const int tid = threadIdx.x;
  const int rowBase = blockIdx.x * 64;
  const int wave = tid >> 6;
  const int lane = tid & 63;
  const int m16 = lane & 15;
  const int quad = lane >> 4;
  {
    int sRow = tid >> 2;
    int sK8 = (tid & 3) * 8;
    int row = rowBase + sRow;
    uint4 av = make_uint4(0, 0, 0, 0);
    if (row < M) av = *(const uint4*)(Ah + (size_t)row * 32 + sK8);
    *(uint4*)&Al[sRow][sK8] = av;
  }
#pragma unroll
  for (int l = 0; l < 2; ++l) {
    int lin = tid + l * 256;
    int bRow = lin >> 2;
    int bK8 = (lin & 3) * 8;
    *(uint4*)&Bl[bRow][bK8] = *(const uint4*)(W0h + (size_t)bRow * 32 + bK8);
  }
  __syncthreads();
  short8 a = *(const short8*)&Al[wave * 16 + m16][quad * 8];
  floatx4 acc[8];
#pragma unroll
  for (int c = 0; c < 8; ++c) {
    floatx4 z;
    z[0] = 0.f; z[1] = 0.f; z[2] = 0.f; z[3] = 0.f;
    short8 b = *(const short8*)&Bl[c * 16 + m16][quad * 8];
    acc[c] = __builtin_amdgcn_mfma_f32_16x16x32_f16(a, b, z, 0, 0, 0);
  }
#pragma unroll
  for (int c = 0; c < 8; ++c) {
    int col = c * 16 + m16;
    float bv = b0[col];
#pragma unroll
    for (int r = 0; r < 4; ++r)
      Hs[wave * 16 + quad * 4 + r][col] = f2h(fmaxf(acc[c][r] + bv, 0.f));
  }
  __syncthreads();
  const uint4* ls = (const uint4*)&Hs[0][0];
  uint4* gd = (uint4*)(h0h + (size_t)rowBase * 128);
#pragma unroll
  for (int i = 0; i < 4; ++i) {
    int idx = tid + i * 256;
    if (rowBase + (idx >> 4) < M) gd[idx] = ls[idx];
  }
}

// ---------------- fused prep: weights(fp16) + counters zero + copyx + out init
__global__ void prep_all_kernel(const float* __restrict__ W0, const float* __restrict__ W1,
                                const float* __restrict__ W2, ushort* __restrict__ W0h,
                                ushort* __restrict__ Wt1, ushort* __restrict__ Wt2,
                                int* __restrict__ degcnt, int* __restrict__ nodecnt,
                                const float* __restrict__ x, float4* __restrict__ Tb,
                                ushort* __restrict__ Ah,
                                float* __restrict__ out, const float* __restrict__ linb) {
  int i = blockIdx.x * 256 + threadIdx.x;
  if (i < 768 * 128) {
    int k = i / 128, n = i - k * 128;
    Wt1[(size_t)n * 768 + k] = f2h(W1[i]);
  } else if (i < 768 * 128 + 768 * 256) {
    int i2 = i - 768 * 128;
    int k = i2 / 256, n = i2 - k * 256;
    Wt2[(size_t)n * 768 + k] = f2h(W2[i2]);
  } else if (i < WPREP_TOTAL) {
    int i3 = i - 768 * 128 - 768 * 256;
    int col = i3 >> 5, k = i3 & 31;
    int a = k >> 2, jj = k & 3;
    float v = (k < 24 && jj < 3) ? W0[(a * 3 + jj) * 128 + col] : 0.f;
    W0h[(size_t)col * 32 + k] = f2h(v);
  } else if (i < WPREP_TOTAL + DEG_TOTAL) {
    degcnt[i - WPREP_TOTAL] = 0;
  } else if (i < WPREP_TOTAL + DEG_TOTAL + NPAD_TOTAL) {
    nodecnt[i - (WPREP_TOTAL + DEG_TOTAL)] = 0;
  } else if (i < WPREP_TOTAL + DEG_TOTAL + NPAD_TOTAL + cN0) {
    int r = i - (WPREP_TOTAL + DEG_TOTAL + NPAD_TOTAL);
    float x0 = x[3 * r], x1 = x[3 * r + 1], x2 = x[3 * r + 2];
    Tb[r] = make_float4(x0, x1, x2, 0.f);
    uint4 z = make_uint4(0, 0, 0, 0);
    uint4 first = make_uint4(f2h(x0) | ((unsigned)f2h(x1) << 16), (unsigned)f2h(x2), 0, 0);
    uint4* p = (uint4*)(Ah + (size_t)r * 32);
    p[0] = first; p[1] = z; p[2] = z; p[3] = z;
  } else if (i < PREP_ALL_TOTAL) {
    int o = i - (WPREP_TOTAL + DEG_TOTAL + NPAD_TOTAL + cN0);
    out[o] = linb[o];
  }
}

// ---------------- main GEMM (fp16 A/B; optional fp16-only output) --------
template <int RELU, int OUTH>
__global__ __launch_bounds__(256, 2) void gemm_mfma_kernel(
    const ushort* __restrict__ Th, const ushort* __restrict__ Wt,
    const float* __restrict__ bias, float* __restrict__ C, ushort* __restrict__ Ch,
    int M, int N) {
  __shared__ ushort Al[64][40];
  __shared__ ushort Bl[128][40];
  __shared__ ushort Hs[64][128];
  const int tid = threadIdx.x;
  const int rowBase = blockIdx.x * 64;
  const int colBase = blockIdx.y * 128;
  const int wave = tid >> 6;
  const int lane = tid & 63;
  const int m16 = lane & 15;
  const int quad = lane >> 4;
  const size_t Mstride = (size_t)M * 128;

  floatx4 acc[8];
#pragma unroll
  for (int c = 0; c < 8; ++c)
#pragma unroll
    for (int r = 0; r < 4; ++r) acc[c][r] = 0.f;

  const int sRow = tid >> 2;
  const int sK8 = (tid & 3) * 8;
  const int growA = rowBase + sRow;
  const bool aValid = growA < M;

  for (int kc = 0; kc < 24; ++kc) {
    uint4 av = make_uint4(0, 0, 0, 0);
    if (aValid)
      av = *(const uint4*)(Th + (size_t)(kc >> 2) * Mstride + (size_t)growA * 128
                           + ((kc & 3) << 5) + sK8);
    *(uint4*)&Al[sRow][sK8] = av;
#pragma unroll
    for (int l = 0; l < 2; ++l) {
      int lin = tid + l * 256;
      int bRow = lin >> 2;
      int bK8 = (lin & 3) * 8;
      *(uint4*)&Bl[bRow][bK8] =
          *(const uint4*)(Wt + (size_t)(colBase + bRow) * 768 + kc * 32 + bK8);
    }
    __syncthreads();

    short8 a = *(const short8*)&Al[wave * 16 + m16][quad * 8];
#pragma unroll
    for (int c = 0; c < 8; ++c) {
      short8 b = *(const short8*)&Bl[c * 16 + m16][quad * 8];
      acc[c] = __builtin_amdgcn_mfma_f32_16x16x32_f16(a, b, acc[c], 0, 0, 0);
    }
    __syncthreads();
  }

  if (OUTH) {
#pragma unroll
    for (int c = 0; c < 8; ++c) {
      int col = c * 16 + m16;
      float bv = bias[col];
#pragma unroll
      for (int r = 0; r < 4; ++r) {
        float v = acc[c][r] + bv;
        if (RELU) v = fmaxf(v, 0.f);
        Hs[wave * 16 + quad * 4 + r][col] = f2h(v);
      }
    }
    __syncthreads();
    const uint4* ls = (const uint4*)&Hs[0][0];
    uint4* gd = (uint4*)(Ch + (size_t)rowBase * 128);
#pragma unroll
    for (int i = 0; i < 4; ++i) {
      int idx = tid + i * 256;
      if (rowBase + (idx >> 4) < M) gd[idx] = ls[idx];
    }
  } else {
#pragma unroll
    for (int c = 0; c < 8; ++c) {
      int col = colBase + c * 16 + m16;
      float bv = bias[col];
#pragma unroll
      for (int r = 0; r < 4; ++r) {
        int row = rowBase + wave * 16 + quad * 4 + r;
        if (row < M) {
          float v = acc[c][r] + bv;
          if (RELU) v = fmaxf(v, 0.f);
          C[(size_t)row * N + col] = v;
        }
      }
    }
  }
}

// ---------------- linear head ----------------
__global__ __launch_bounds__(256) void linear_kernel(const float* __restrict__ Wl,
                                                     const float* __restrict__ h,
                                                     float* __restrict__ out, int D) {
  float p[10];
#pragma unroll
  for (int j = 0; j < 10; ++j) p[j] = 0.f;
  int stride = gridDim.x * blockDim.x;
  for (int i = blockIdx.x * blockDim.x + threadIdx.x; i < D; i += stride) {
    float hv = h[i];
#pragma unroll
    for (int j = 0; j < 10; ++j) p[j] += Wl[(size_t)j * D + i] * hv;
  }
#pragma unroll
  for (int j = 0; j < 10; ++j) {
#pragma unroll
    for (int off = 32; off > 0; off >>= 1) p[j] += __shfl_down(p[j], off, 64);
  }
  __shared__ float s[4][10];
  int wave = threadIdx.x >> 6, lane = threadIdx.x & 63;
  if (lane == 0) {
#pragma unroll
    for (int j = 0; j < 10; ++j) s[wave][j] = p[j];
  }
  __syncthreads();
  if (threadIdx.x < 10) {
    float t = s[0][threadIdx.x] + s[1][threadIdx.x] + s[2][threadIdx.x] + s[3][threadIdx.x];
    atomicAdd(&out[threadIdx.x], t);
  }
}

// ---------------- host orchestration ----------------
extern "C" void kernel_launch(void* const* d_in, const int* in_sizes, int n_in,
                              void* d_out, int out_size, void* d_ws, size_t ws_size,
                              hipStream_t stream) {
  const float* x    = (const float*)d_in[0];
  const int*   ei0  = (const int*)d_in[1];
  const int*   ei1  = (const int*)d_in[2];
  const int*   ei2  = (const int*)d_in[3];
  const float* W0   = (const float*)d_in[4];
  const float* b0   = (const float*)d_in[5];
  const float* W1   = (const float*)d_in[6];
  const float* b1   = (const float*)d_in[7];
  const float* W2   = (const float*)d_in[8];
  const float* b2   = (const float*)d_in[9];
  const int*   D0r  = (const int*)d_in[10];
  const int*   D0c  = (const int*)d_in[11];
  const float* D0v  = (const float*)d_in[12];
  const int*   D1r  = (const int*)d_in[13];
  const int*   D1c  = (const int*)d_in[14];
  const float* D1v  = (const float*)d_in[15];
  const float* linW = (const float*)d_in[16];
  const float* linb = (const float*)d_in[17];
  float* out = (float*)d_out;
  (void)in_sizes; (void)n_in; (void)out_size; (void)ws_size;

  const int* src0 = ei0;            const int* dst0 = ei0 + cE0;
  const int* src1 = ei1;            const int* dst1 = ei1 + cE1;
  const int* src2 = ei2;            const int* dst2 = ei2 + cE2;

  float* ws = (float*)d_ws;
  size_t off = 0;
  auto alloc = [&](size_t n) {
    float* p = ws + off;
    off += (n + 63) & ~size_t(63);
    return p;
  };
  float* dinv       = alloc(DEG_TOTAL);
  int*   degcnt     = (int*)alloc(DEG_TOTAL);
  int*   nodecnt    = (int*)alloc(NPAD_TOTAL);
  int*   cursor     = (int*)alloc(NPAD_TOTAL);
  int*   blockTot   = (int*)alloc(TB);
  int*   blockBase  = (int*)alloc(TB);
  int2*  csrPairs   = (int2*)alloc((size_t)2 * E_TOTAL);
  int*   offArr     = (int*)alloc(NPAD_TOTAL);
  ushort* W0h       = (ushort*)alloc(128 * 32 / 2);
  ushort* Wt1       = (ushort*)alloc(768 * 128 / 2);
  ushort* Wt2       = (ushort*)alloc(768 * 256 / 2);
  float4* Tb0       = (float4*)alloc((size_t)6 * cN0 * 4);
  ushort* Ah0       = (ushort*)alloc((size_t)cN0 * 16);
  ushort* h0h       = (ushort*)alloc((size_t)cN0 * 64);
  float* Tlvl1      = alloc((size_t)6 * cN1 * 128);
  ushort* Th1       = (ushort*)alloc((size_t)6 * cN1 * 64);
  ushort* out1h     = (ushort*)alloc((size_t)cN1 * 64);
  float* Tlvl2      = alloc((size_t)6 * cN2 * 128);
  ushort* Th2       = (ushort*)alloc((size_t)6 * cN2 * 64);
  float* out2       = alloc((size_t)cN2 * 256);

  auto nb = [](long long n) { return (unsigned)((n + 255) / 256); };

  // ---- prep: weights + counter zero + copyx + out init ----
  prep_all_kernel<<<nb(PREP_ALL_TOTAL), 256, 0, stream>>>(
      W0, W1, W2, W0h, Wt1, Wt2, degcnt, nodecnt, x, Tb0, Ah0, out, linb);

  // ---- direct CSR build ----
  c1_count_kernel<<<TCB, 256, 0, stream>>>(dst0, dst1, dst2, D0r, D1r,
                                           src0, src1, src2, degcnt, nodecnt);
  s1_scan_kernel<<<TB, 256, 0, stream>>>(nodecnt, offArr, blockTot, degcnt, dinv);
  s2_scan_kernel<<<5, 256, 0, stream>>>(blockTot, blockBase);
  s3_fix_kernel<<<TB, 256, 0, stream>>>(offArr, cursor, blockBase);
  scatter_kernel<<<TCB, 256, 0, stream>>>(dst0, src0, dst1, src1, dst2, src2,
                                          D0r, D0c, D0v, D1r, D1c, D1v,
                                          dinv, cursor, csrPairs);

  auto seg_off   = [&](int s) { return offArr + NBASE[s]; };
  auto seg_pairs = [&](int s) { return csrPairs + EBASE[s]; };

  // ================= Level 0 (F=3 -> 128) =================
  {
    auto Tk = [&](int k) { return Tb0 + (size_t)k * cN0; };
    csr_prop3_kernel<<<nb((size_t)4 * cN0), 256, 0, stream>>>(seg_off(0), seg_pairs(0),
        Tk(0), Tk(1), nullptr, 1.f, cN0, Ah0, 1);
    csr_prop3_kernel<<<nb((size_t)4 * cN0), 256, 0, stream>>>(seg_off(0), seg_pairs(0),
        Tk(1), Tk(2), Tk(0), 2.f, cN0, Ah0, 2);
    csr_prop3_kernel<<<nb((size_t)4 * cN0), 256, 0, stream>>>(seg_off(0), seg_pairs(0),
        Tk(2), Tk(3), Tk(1), 2.f, cN0, Ah0, 3);
    csr_prop3_kernel<<<nb((size_t)4 * cN0), 256, 0, stream>>>(seg_off(0), seg_pairs(0),
        Tk(3), Tk(4), Tk(2), 2.f, cN0, Ah0, 4);
    csr_prop3_kernel<<<nb((size_t)4 * cN0), 256, 0, stream>>>(seg_off(0), seg_pairs(0),
        Tk(4), Tk(5), Tk(3), 2.f, cN0, Ah0, 5);
  }
  // MFMA h0 (fp16 out), then pool0 fp16 gather -> Tlvl1 block 0
  h0_mfma_kernel<<<(cN0 + 63) / 64, 256, 0, stream>>>(Ah0, W0h, b0, h0h, cN0);
  csr_prop128h_kernel<<<(cN1 + 7) / 8, 256, 0, stream>>>(
      seg_off(3), seg_pairs(3), h0h, Tlvl1, Th1, nullptr, 1.f, cN1);

  // ================= Level 1 =================
  {
    auto Tk  = [&](int k) { return Tlvl1 + (size_t)k * cN1 * 128; };
    auto Thk = [&](int k) { return Th1 + (size_t)k * cN1 * 128; };
    auto prop = [&](int kin, int kout, int kprev, float scale, bool needF32) {
      csr_prop128h_kernel<<<(cN1 + 7) / 8, 256, 0, stream>>>(
          seg_off(1), seg_pairs(1), Thk(kin), needF32 ? Tk(kout) : nullptr, Thk(kout),
          (kprev >= 0) ? Tk(kprev) : nullptr, scale, cN1);
    };
    prop(0, 1, -1, 1.f, true);
    prop(1, 2, 0, 2.f, true);
    prop(2, 3, 1, 2.f, true);
    prop(3, 4, 2, 2.f, true);
    prop(4, 5, 3, 2.f, false);
    dim3 g((cN1 + 63) / 64, 1);
    gemm_mfma_kernel<1, 1><<<g, 256, 0, stream>>>(Th1, Wt1, b1, nullptr, out1h,
                                                  cN1, 128);
  }

  // pool1: out1h (fp16) -> Tlvl2 block 0
  csr_prop128h_kernel<<<(cN2 + 7) / 8, 256, 0, stream>>>(
      seg_off(4), seg_pairs(4), out1h, Tlvl2, Th2, nullptr, 1.f, cN2);

  // ================= Level 2 (no relu, N=256) =================
  {
    auto Tk  = [&](int k) { return Tlvl2 + (size_t)k * cN2 * 128; };
    auto Thk = [&](int k) { return Th2 + (size_t)k * cN2 * 128; };
    auto prop = [&](int kin, int kout, int kprev, float scale, bool needF32) {
      csr_prop128h_kernel<<<(cN2 + 7) / 8, 256, 0, stream>>>(
          seg_off(2), seg_pairs(2), Thk(kin), needF32 ? Tk(kout) : nullptr, Thk(kout),
          (kprev >= 0) ? Tk(kprev) : nullptr, scale, cN2);
    };
    prop(0, 1, -1, 1.f, true);
    prop(1, 2, 0, 2.f, true);
    prop(2, 3, 1, 2.f, true);
    prop(3, 4, 2, 2.f, true);
    prop(4, 5, 3, 2.f, false);
    dim3 g((cN2 + 63) / 64, 2);
    gemm_mfma_kernel<0, 0><<<g, 256, 0, stream>>>(Th2, Wt2, b2, out2, nullptr,
                                                  cN2, 256);
  }

  // ---- linear head (out pre-initialized with linb in prep) ----
  linear_kernel<<<512, 256, 0, stream>>>(linW, out2, out, cD);
}

// Round 6
// 417.643 us; speedup vs baseline: 4.0806x; 1.1563x over previous
//
#include <hip/hip_runtime.h>

// ChebClassifier R15: best-of-R12+R14.
// Build = R12 two-phase radix CSR (c1 fused degcnt -> c2a -> c2b -> c3_dst
// -> dcsr): sequential bucket-region writes, no 8x line amplification
// (R14's direct scatter was 70us, WRITE 61MB for 7.3MB payload).
// Level-0 prop = R14 4-lane/row quad-shuffle (4x occupancy vs 1 thread/row).
// fp16 side-channel everywhere (R12). absmax 0.0078 expected unchanged.

namespace {
constexpr int cN0 = 100000, cN1 = 25000, cN2 = 6250;
constexpr int cE0 = 600000, cE1 = 150000, cE2 = 37500;
constexpr int cD  = cN2 * 256;

// jobs 0-4: dst-keyed CSR builds (conv0, conv1, conv2, pool0, pool1)
constexpr int JN[5]  = {cN0, cN1, cN2, cN1, cN2};
constexpr int JE[5]  = {cE0, cE1, cE2, 100000, 25000};
constexpr int JB[5]  = {391, 98, 25, 98, 25};
constexpr int JBBASE[6] = {0, 391, 489, 514, 612, 637};
constexpr int TB = 637;
constexpr int JCB[5] = {293, 74, 19, 49, 13};
constexpr int JCBASE[6] = {0, 293, 367, 386, 435, 448};
constexpr int TCB = 448;
constexpr int CHUNK = 2048;
constexpr int BSTRIDE = 400;

constexpr int EBASE[5]   = {0, 600000, 750000, 787500, 887500};
constexpr int E_TOTAL    = 912500;
constexpr int NBASE[5]   = {0, 100096, 125184, 131584, 156672};
constexpr int NPAD_TOTAL = 163072;
constexpr int DEGBASE[3] = {0, 100000, 125000};
constexpr int DEG_TOTAL  = 131250;
constexpr int WPREP_TOTAL = 768 * 128 + 768 * 256 + 128 * 32;
constexpr int PREP_ALL_TOTAL = WPREP_TOTAL + DEG_TOTAL + cN0 + 10;
}

typedef __attribute__((ext_vector_type(8))) short short8;
typedef __attribute__((ext_vector_type(4))) float floatx4;

__device__ inline ushort f2h(float f) {
  union { _Float16 h; ushort u; } v;
  v.h = (_Float16)f;
  return v.u;
}
__device__ inline float h2f(unsigned lo16) {
  union { ushort u; _Float16 h; } v;
  v.u = (ushort)lo16;
  return (float)v.h;
}

__device__ inline int job_of_cb(int cb) {
  int j = 0;
  while (cb >= JCBASE[j + 1]) ++j;
  return j;
}
__device__ inline int job_of_bucket(int g) {
  int j = 0;
  while (g >= JBBASE[j + 1]) ++j;
  return j;
}

// ---------------- two-phase radix CSR build (R12) ----------------
__global__ __launch_bounds__(256) void c1_count_kernel(
    const int* __restrict__ k0, const int* __restrict__ k1, const int* __restrict__ k2,
    const int* __restrict__ k3, const int* __restrict__ k4,
    const int* __restrict__ s0, const int* __restrict__ s1, const int* __restrict__ s2,
    int* __restrict__ degcnt, int* __restrict__ cntCB) {
  __shared__ int cnt[BSTRIDE];
  int cb = blockIdx.x;
  int j = job_of_cb(cb);
  int lb = cb - JCBASE[j];
  const int* keys;
  const int* srck = nullptr;
  int dbase = 0;
  switch (j) {
    case 0: keys = k0; srck = s0; dbase = DEGBASE[0]; break;
    case 1: keys = k1; srck = s1; dbase = DEGBASE[1]; break;
    case 2: keys = k2; srck = s2; dbase = DEGBASE[2]; break;
    case 3: keys = k3; break;
    default: keys = k4; break;
  }
  int nB = JB[j];
  for (int b = threadIdx.x; b < nB; b += 256) cnt[b] = 0;
  __syncthreads();
  int e0 = lb * CHUNK;
  int e1 = min(e0 + CHUNK, JE[j]);
  for (int e = e0 + threadIdx.x; e < e1; e += 256) {
    atomicAdd(&cnt[keys[e] >> 8], 1);
    if (srck) atomicAdd(&degcnt[dbase + srck[e]], 1);
  }
  __syncthreads();
  for (int b = threadIdx.x; b < nB; b += 256)
    cntCB[cb * BSTRIDE + b] = cnt[b];
}

__global__ __launch_bounds__(256) void c2a_scan_kernel(int* __restrict__ cntCB,
                                                       int* __restrict__ bucketTot,
                                                       const int* __restrict__ degcnt,
                                                       float* __restrict__ dinv) {
  __shared__ int s[256];
  int g = blockIdx.x;
  int j = job_of_bucket(g);
  int b = g - JBBASE[j];
  int cb0 = JCBASE[j], nCB = JCB[j];
  int carry = 0;
  for (int c0 = 0; c0 < nCB; c0 += 256) {
    int i = c0 + threadIdx.x;
    int v = (i < nCB) ? cntCB[(cb0 + i) * BSTRIDE + b] : 0;
    s[threadIdx.x] = v;
    __syncthreads();
    for (int d = 1; d < 256; d <<= 1) {
      int t = (threadIdx.x >= d) ? s[threadIdx.x - d] : 0;
      __syncthreads();
      s[threadIdx.x] += t;
      __syncthreads();
    }
    if (i < nCB) cntCB[(cb0 + i) * BSTRIDE + b] = carry + s[threadIdx.x] - v;
    carry += s[255];
    __syncthreads();
  }
  if (threadIdx.x == 0) bucketTot[g] = carry;
  // fused dinv finalize (degcnt complete after c1)
  int idx = blockIdx.x * 256 + threadIdx.x;
  if (idx < DEG_TOTAL) {
    int c = degcnt[idx];
    dinv[idx] = (c > 0) ? rsqrtf((float)c) : 0.f;
  }
}

__global__ __launch_bounds__(256) void c2b_scan_kernel(const int* __restrict__ bucketTot,
                                                       int* __restrict__ bucketBase) {
  __shared__ int s[256];
  int j = blockIdx.x;
  int g0 = JBBASE[j], nB = JB[j];
  int carry = 0;
  for (int c0 = 0; c0 < nB; c0 += 256) {
    int i = c0 + threadIdx.x;
    int v = (i < nB) ? bucketTot[g0 + i] : 0;
    s[threadIdx.x] = v;
    __syncthreads();
    for (int d = 1; d < 256; d <<= 1) {
      int t = (threadIdx.x >= d) ? s[threadIdx.x - d] : 0;
      __syncthreads();
      s[threadIdx.x] += t;
      __syncthreads();
    }
    if (i < nB) bucketBase[g0 + i] = carry + s[threadIdx.x] - v;
    carry += s[255];
    __syncthreads();
  }
}

__global__ __launch_bounds__(256) void c3_dst_kernel(
    const int* __restrict__ d0, const int* __restrict__ s0,
    const int* __restrict__ d1, const int* __restrict__ s1,
    const int* __restrict__ d2, const int* __restrict__ s2,
    const int* __restrict__ p0r, const int* __restrict__ p0c, const float* __restrict__ p0v,
    const int* __restrict__ p1r, const int* __restrict__ p1c, const float* __restrict__ p1v,
    const float* __restrict__ dinv,
    const int* __restrict__ cntCB, const int* __restrict__ bucketBase,
    int2* __restrict__ scatPairs) {
  __shared__ int base[BSTRIDE];
  int cb = blockIdx.x;
  int j = job_of_cb(cb);
  int lb = cb - JCBASE[j];
  const int* dk; const int* sk; const float* vv = nullptr;
  switch (j) {
    case 0: dk = d0; sk = s0; break;
    case 1: dk = d1; sk = s1; break;
    case 2: dk = d2; sk = s2; break;
    case 3: dk = p0r; sk = p0c; vv = p0v; break;
    default: dk = p1r; sk = p1c; vv = p1v; break;
  }
  int nB = JB[j];
  for (int b = threadIdx.x; b < nB; b += 256)
    base[b] = EBASE[j] + bucketBase[JBBASE[j] + b] + cntCB[cb * BSTRIDE + b];
  __syncthreads();
  int e0 = lb * CHUNK;
  int e1 = min(e0 + CHUNK, JE[j]);
  for (int e = e0 + threadIdx.x; e < e1; e += 256) {
    int d = dk[e];
    int s = sk[e];
    float w;
    if (j < 3) w = -(dinv[DEGBASE[j] + s] * dinv[DEGBASE[j] + d]);
    else w = vv[e];
    int pos = atomicAdd(&base[d >> 8], 1);
    scatPairs[pos] = make_int2(((d & 255) << 17) | s, __float_as_int(w));
  }
}

__global__ __launch_bounds__(256) void dcsr_kernel(const int2* __restrict__ scatPairs,
                                                   const int* __restrict__ bucketTot,
                                                   const int* __restrict__ bucketBase,
                                                   int* __restrict__ off,
                                                   int2* __restrict__ csrPairs) {
  __shared__ int cnt[256];
  __shared__ int sArr[256];
  __shared__ int cur[256];
  int g = blockIdx.x;
  int j = job_of_bucket(g);
  int b = g - JBBASE[j];
  int relBase = bucketBase[g];
  int st = EBASE[j] + relBase;
  int en = st + bucketTot[g];
  cnt[threadIdx.x] = 0;
  __syncthreads();
  for (int idx = st + threadIdx.x; idx < en; idx += 256)
    atomicAdd(&cnt[scatPairs[idx].x >> 17], 1);
  __syncthreads();
  int v = cnt[threadIdx.x];
  sArr[threadIdx.x] = v;
  __syncthreads();
  for (int d = 1; d < 256; d <<= 1) {
    int t = (threadIdx.x >= d) ? sArr[threadIdx.x - d] : 0;
    __syncthreads();
    sArr[threadIdx.x] += t;
    __syncthreads();
  }
  int excl = sArr[threadIdx.x] - v;
  int node = b * 256 + threadIdx.x;
  if (node < JN[j]) off[NBASE[j] + node] = relBase + excl;
  if (threadIdx.x == 0 && b == JB[j] - 1) off[NBASE[j] + JN[j]] = JE[j];
  cur[threadIdx.x] = st + excl;
  __syncthreads();
  for (int idx = st + threadIdx.x; idx < en; idx += 256) {
    int2 p = scatPairs[idx];
    int dl = p.x >> 17;
    int s = p.x & 0x1FFFF;
    int pos = atomicAdd(&cur[dl], 1);
    csrPairs[pos] = make_int2(s, p.y);
  }
}

// ---------------- unified prop/pool over 128-wide rows ----------------
__global__ __launch_bounds__(256) void csr_prop128h_kernel(
    const int* __restrict__ off, const int2* __restrict__ pairs,
    const ushort* __restrict__ hh, float* __restrict__ y, ushort* __restrict__ yh,
    const float* __restrict__ prev, float scale, int N) {
  int r = blockIdx.x * 8 + (threadIdx.x >> 5);
  int l = threadIdx.x & 31;
  if (r >= N) return;
  int s = off[r], e = off[r + 1];
  const uint2* h2 = (const uint2*)hh;
  float ax = 0.f, ay = 0.f, az = 0.f, aw = 0.f;
  int j = s;
  for (; j + 4 <= e; j += 4) {
    int2 p0 = pairs[j], p1 = pairs[j + 1], p2 = pairs[j + 2], p3 = pairs[j + 3];
    uint2 v0 = h2[(size_t)p0.x * 32 + l];
    uint2 v1 = h2[(size_t)p1.x * 32 + l];
    uint2 v2 = h2[(size_t)p2.x * 32 + l];
    uint2 v3 = h2[(size_t)p3.x * 32 + l];
    float w0 = __int_as_float(p0.y), w1 = __int_as_float(p1.y);
    float w2 = __int_as_float(p2.y), w3 = __int_as_float(p3.y);
    ax += w0 * h2f(v0.x & 0xFFFFu) + w1 * h2f(v1.x & 0xFFFFu)
        + w2 * h2f(v2.x & 0xFFFFu) + w3 * h2f(v3.x & 0xFFFFu);
    ay += w0 * h2f(v0.x >> 16) + w1 * h2f(v1.x >> 16)
        + w2 * h2f(v2.x >> 16) + w3 * h2f(v3.x >> 16);
    az += w0 * h2f(v0.y & 0xFFFFu) + w1 * h2f(v1.y & 0xFFFFu)
        + w2 * h2f(v2.y & 0xFFFFu) + w3 * h2f(v3.y & 0xFFFFu);
    aw += w0 * h2f(v0.y >> 16) + w1 * h2f(v1.y >> 16)
        + w2 * h2f(v2.y >> 16) + w3 * h2f(v3.y >> 16);
  }
  for (; j < e; ++j) {
    int2 p = pairs[j];
    uint2 v0 = h2[(size_t)p.x * 32 + l];
    float w = __int_as_float(p.y);
    ax += w * h2f(v0.x & 0xFFFFu);
    ay += w * h2f(v0.x >> 16);
    az += w * h2f(v0.y & 0xFFFFu);
    aw += w * h2f(v0.y >> 16);
  }
  float4 v = make_float4(scale * ax, scale * ay, scale * az, scale * aw);
  if (prev) {
    float4 pv = ((const float4*)prev)[(size_t)r * 32 + l];
    v.x -= pv.x; v.y -= pv.y; v.z -= pv.z; v.w -= pv.w;
  }
  if (y) ((float4*)y)[(size_t)r * 32 + l] = v;
  uint2 sp = make_uint2(f2h(v.x) | ((unsigned)f2h(v.y) << 16),
                        f2h(v.z) | ((unsigned)f2h(v.w) << 16));
  ((uint2*)yh)[(size_t)r * 32 + l] = sp;
}

// level-0: 4 lanes per row, quad shuffle reduce; fp32 slab + fp16 slot kout
__global__ __launch_bounds__(256) void csr_prop3_kernel(
    const int* __restrict__ off, const int2* __restrict__ pairs,
    const float4* __restrict__ h, float4* __restrict__ y,
    const float4* __restrict__ prev, float scale, int N,
    ushort* __restrict__ yh, int kout) {
  int t = blockIdx.x * 256 + threadIdx.x;
  int r = t >> 2;
  int q = t & 3;
  if (r >= N) return;
  int s = off[r], e = off[r + 1];
  float ax = 0.f, ay = 0.f, az = 0.f;
  for (int j = s + q; j < e; j += 4) {
    int2 p = pairs[j];
    float4 hv = h[p.x];
    float w = __int_as_float(p.y);
    ax += w * hv.x; ay += w * hv.y; az += w * hv.z;
  }
  ax += __shfl_xor(ax, 1); ay += __shfl_xor(ay, 1); az += __shfl_xor(az, 1);
  ax += __shfl_xor(ax, 2); ay += __shfl_xor(ay, 2); az += __shfl_xor(az, 2);
  if (q == 0) {
    float4 v = make_float4(scale * ax, scale * ay, scale * az, 0.f);
    if (prev) {
      float4 pv = prev[r];
      v.x -= pv.x; v.y -= pv.y; v.z -= pv.z;
    }
    y[r] = v;
    uint2 sp = make_uint2(f2h(v.x) | ((unsigned)f2h(v.y) << 16), (unsigned)f2h(v.z));
    *(uint2*)(yh + (size_t)r * 32 + kout * 4) = sp;
  }
}

// h0 = relu(b0 + A[M,32]fp16 @ W0h[32,128]) via single-chunk MFMA; fp16 out
__global__ __launch_bounds__(256, 2) void h0_mfma_kernel(
    const ushort* __restrict__ Ah, const ushort* __restrict__ W0h,
    const float* __restrict__ b0, ushort* __restrict__ h0h, int M) {
  __shared__ ushort Al[64][40];
  __shared__ ushort Bl[128][40];
  __shared__ ushort Hs[64][128];
  const int tid = threadIdx.x;
  const int rowBase = blockIdx.x * 64;
  const int wave = tid >> 6;
  const int lane = tid & 63;
  const int m16 = lane & 15;
  const int quad = lane >> 4;
  {
    int sRow = tid >> 2;
    int sK8 = (tid & 3) * 8;
    int row = rowBase + sRow;
    uint4 av = make_uint4(0, 0, 0, 0);
    if (row < M) av = *(const uint4*)(Ah + (size_t)row * 32 + sK8);
    *(uint4*)&Al[sRow][sK8] = av;
  }
#pragma unroll
  for (int l = 0; l < 2; ++l) {
    int lin = tid + l * 256;
    int bRow = lin >> 2;
    int bK8 = (lin & 3) * 8;
    *(uint4*)&Bl[bRow][bK8] = *(const uint4*)(W0h + (size_t)bRow * 32 + bK8);
  }
  __syncthreads();
  short8 a = *(const short8*)&Al[wave * 16 + m16][quad * 8];
  floatx4 acc[8];
#pragma unroll
  for (int c = 0; c < 8; ++c) {
    floatx4 z;
    z[0] = 0.f; z[1] = 0.f; z[2] = 0.f; z[3] = 0.f;
    short8 b = *(const short8*)&Bl[c * 16 + m16][quad * 8];
    acc[c] = __builtin_amdgcn_mfma_f32_16x16x32_f16(a, b, z, 0, 0, 0);
  }
#pragma unroll
  for (int c = 0; c < 8; ++c) {
    int col = c * 16 + m16;
    float bv = b0[col];
#pragma unroll
    for (int r = 0; r < 4; ++r)
      Hs[wave * 16 + quad * 4 + r][col] = f2h(fmaxf(acc[c][r] + bv, 0.f));
  }
  __syncthreads();
  const uint4* ls = (const uint4*)&Hs[0][0];
  uint4* gd = (uint4*)(h0h + (size_t)rowBase * 128);
#pragma unroll
  for (int i = 0; i < 4; ++i) {
    int idx = tid + i * 256;
    if (rowBase + (idx >> 4) < M) gd[idx] = ls[idx];
  }
}

// ---------------- fused prep: weights(fp16) + degcnt zero + copyx + out init
__global__ void prep_all_kernel(const float* __restrict__ W0, const float* __restrict__ W1,
                                const float* __restrict__ W2, ushort* __restrict__ W0h,
                                ushort* __restrict__ Wt1, ushort* __restrict__ Wt2,
                                int* __restrict__ degcnt,
                                const float* __restrict__ x, float4* __restrict__ Tb,
                                ushort* __restrict__ Ah,
                                float* __restrict__ out, const float* __restrict__ linb) {
  int i = blockIdx.x * 256 + threadIdx.x;
  if (i < 768 * 128) {
    int k = i / 128, n = i - k * 128;
    Wt1[(size_t)n * 768 + k] = f2h(W1[i]);
  } else if (i < 768 * 128 + 768 * 256) {
    int i2 = i - 768 * 128;
    int k = i2 / 256, n = i2 - k * 256;
    Wt2[(size_t)n * 768 + k] = f2h(W2[i2]);
  } else if (i < WPREP_TOTAL) {
    int i3 = i - 768 * 128 - 768 * 256;
    int col = i3 >> 5, k = i3 & 31;
    int a = k >> 2, jj = k & 3;
    float v = (k < 24 && jj < 3) ? W0[(a * 3 + jj) * 128 + col] : 0.f;
    W0h[(size_t)col * 32 + k] = f2h(v);
  } else if (i < WPREP_TOTAL + DEG_TOTAL) {
    degcnt[i - WPREP_TOTAL] = 0;
  } else if (i < WPREP_TOTAL + DEG_TOTAL + cN0) {
    int r = i - (WPREP_TOTAL + DEG_TOTAL);
    float x0 = x[3 * r], x1 = x[3 * r + 1], x2 = x[3 * r + 2];
    Tb[r] = make_float4(x0, x1, x2, 0.f);
    uint4 z = make_uint4(0, 0, 0, 0);
    uint4 first = make_uint4(f2h(x0) | ((unsigned)f2h(x1) << 16), (unsigned)f2h(x2), 0, 0);
    uint4* p = (uint4*)(Ah + (size_t)r * 32);
    p[0] = first; p[1] = z; p[2] = z; p[3] = z;
  } else if (i < PREP_ALL_TOTAL) {
    int o = i - (WPREP_TOTAL + DEG_TOTAL + cN0);
    out[o] = linb[o];
  }
}

// ---------------- main GEMM (fp16 A/B; optional fp16-only output) --------
template <int RELU, int OUTH>
__global__ __launch_bounds__(256, 2) void gemm_mfma_kernel(
    const ushort* __restrict__ Th, const ushort* __restrict__ Wt,
    const float* __restrict__ bias, float* __restrict__ C, ushort* __restrict__ Ch,
    int M, int N) {
  __shared__ ushort Al[64][40];
  __shared__ ushort Bl[128][40];
  __shared__ ushort Hs[64][128];
  const int tid = threadIdx.x;
  const int rowBase = blockIdx.x * 64;
  const int colBase = blockIdx.y * 128;
  const int wave = tid >> 6;
  const int lane = tid & 63;
  const int m16 = lane & 15;
  const int quad = lane >> 4;
  const size_t Mstride = (size_t)M * 128;

  floatx4 acc[8];
#pragma unroll
  for (int c = 0; c < 8; ++c)
#pragma unroll
    for (int r = 0; r < 4; ++r) acc[c][r] = 0.f;

  const int sRow = tid >> 2;
  const int sK8 = (tid & 3) * 8;
  const int growA = rowBase + sRow;
  const bool aValid = growA < M;

  for (int kc = 0; kc < 24; ++kc) {
    uint4 av = make_uint4(0, 0, 0, 0);
    if (aValid)
      av = *(const uint4*)(Th + (size_t)(kc >> 2) * Mstride + (size_t)growA * 128
                           + ((kc & 3) << 5) + sK8);
    *(uint4*)&Al[sRow][sK8] = av;
#pragma unroll
    for (int l = 0; l < 2; ++l) {
      int lin = tid + l * 256;
      int bRow = lin >> 2;
      int bK8 = (lin & 3) * 8;
      *(uint4*)&Bl[bRow][bK8] =
          *(const uint4*)(Wt + (size_t)(colBase + bRow) * 768 + kc * 32 + bK8);
    }
    __syncthreads();

    short8 a = *(const short8*)&Al[wave * 16 + m16][quad * 8];
#pragma unroll
    for (int c = 0; c < 8; ++c) {
      short8 b = *(const short8*)&Bl[c * 16 + m16][quad * 8];
      acc[c] = __builtin_amdgcn_mfma_f32_16x16x32_f16(a, b, acc[c], 0, 0, 0);
    }
    __syncthreads();
  }

  if (OUTH) {
#pragma unroll
    for (int c = 0; c < 8; ++c) {
      int col = c * 16 + m16;
      float bv = bias[col];
#pragma unroll
      for (int r = 0; r < 4; ++r) {
        float v = acc[c][r] + bv;
        if (RELU) v = fmaxf(v, 0.f);
        Hs[wave * 16 + quad * 4 + r][col] = f2h(v);
      }
    }
    __syncthreads();
    const uint4* ls = (const uint4*)&Hs[0][0];
    uint4* gd = (uint4*)(Ch + (size_t)rowBase * 128);
#pragma unroll
    for (int i = 0; i < 4; ++i) {
      int idx = tid + i * 256;
      if (rowBase + (idx >> 4) < M) gd[idx] = ls[idx];
    }
  } else {
#pragma unroll
    for (int c = 0; c < 8; ++c) {
      int col = colBase + c * 16 + m16;
      float bv = bias[col];
#pragma unroll
      for (int r = 0; r < 4; ++r) {
        int row = rowBase + wave * 16 + quad * 4 + r;
        if (row < M) {
          float v = acc[c][r] + bv;
          if (RELU) v = fmaxf(v, 0.f);
          C[(size_t)row * N + col] = v;
        }
      }
    }
  }
}

// ---------------- linear head ----------------
__global__ __launch_bounds__(256) void linear_kernel(const float* __restrict__ Wl,
                                                     const float* __restrict__ h,
                                                     float* __restrict__ out, int D) {
  float p[10];
#pragma unroll
  for (int j = 0; j < 10; ++j) p[j] = 0.f;
  int stride = gridDim.x * blockDim.x;
  for (int i = blockIdx.x * blockDim.x + threadIdx.x; i < D; i += stride) {
    float hv = h[i];
#pragma unroll
    for (int j = 0; j < 10; ++j) p[j] += Wl[(size_t)j * D + i] * hv;
  }
#pragma unroll
  for (int j = 0; j < 10; ++j) {
#pragma unroll
    for (int off = 32; off > 0; off >>= 1) p[j] += __shfl_down(p[j], off, 64);
  }
  __shared__ float s[4][10];
  int wave = threadIdx.x >> 6, lane = threadIdx.x & 63;
  if (lane == 0) {
#pragma unroll
    for (int j = 0; j < 10; ++j) s[wave][j] = p[j];
  }
  __syncthreads();
  if (threadIdx.x < 10) {
    float t = s[0][threadIdx.x] + s[1][threadIdx.x] + s[2][threadIdx.x] + s[3][threadIdx.x];
    atomicAdd(&out[threadIdx.x], t);
  }
}

// ---------------- host orchestration ----------------
extern "C" void kernel_launch(void* const* d_in, const int* in_sizes, int n_in,
                              void* d_out, int out_size, void* d_ws, size_t ws_size,
                              hipStream_t stream) {
  const float* x    = (const float*)d_in[0];
  const int*   ei0  = (const int*)d_in[1];
  const int*   ei1  = (const int*)d_in[2];
  const int*   ei2  = (const int*)d_in[3];
  const float* W0   = (const float*)d_in[4];
  const float* b0   = (const float*)d_in[5];
  const float* W1   = (const float*)d_in[6];
  const float* b1   = (const float*)d_in[7];
  const float* W2   = (const float*)d_in[8];
  const float* b2   = (const float*)d_in[9];
  const int*   D0r  = (const int*)d_in[10];
  const int*   D0c  = (const int*)d_in[11];
  const float* D0v  = (const float*)d_in[12];
  const int*   D1r  = (const int*)d_in[13];
  const int*   D1c  = (const int*)d_in[14];
  const float* D1v  = (const float*)d_in[15];
  const float* linW = (const float*)d_in[16];
  const float* linb = (const float*)d_in[17];
  float* out = (float*)d_out;
  (void)in_sizes; (void)n_in; (void)out_size; (void)ws_size;

  const int* src0 = ei0;            const int* dst0 = ei0 + cE0;
  const int* src1 = ei1;            const int* dst1 = ei1 + cE1;
  const int* src2 = ei2;            const int* dst2 = ei2 + cE2;

  float* ws = (float*)d_ws;
  size_t off = 0;
  auto alloc = [&](size_t n) {
    float* p = ws + off;
    off += (n + 63) & ~size_t(63);
    return p;
  };
  float* dinv       = alloc(DEG_TOTAL);
  int*   degcnt     = (int*)alloc(DEG_TOTAL);
  int*   cntCB      = (int*)alloc((size_t)TCB * BSTRIDE);
  int*   bucketTot  = (int*)alloc(TB);
  int*   bucketBase = (int*)alloc(TB);
  int2*  scatPairs  = (int2*)alloc((size_t)2 * E_TOTAL);
  int2*  csrPairs   = (int2*)alloc((size_t)2 * E_TOTAL);
  int*   offArr     = (int*)alloc(NPAD_TOTAL);
  ushort* W0h       = (ushort*)alloc(128 * 32 / 2);
  ushort* Wt1       = (ushort*)alloc(768 * 128 / 2);
  ushort* Wt2       = (ushort*)alloc(768 * 256 / 2);
  float4* Tb0       = (float4*)alloc((size_t)6 * cN0 * 4);
  ushort* Ah0       = (ushort*)alloc((size_t)cN0 * 16);
  ushort* h0h       = (ushort*)alloc((size_t)cN0 * 64);
  float* Tlvl1      = alloc((size_t)6 * cN1 * 128);
  ushort* Th1       = (ushort*)alloc((size_t)6 * cN1 * 64);
  ushort* out1h     = (ushort*)alloc((size_t)cN1 * 64);
  float* Tlvl2      = alloc((size_t)6 * cN2 * 128);
  ushort* Th2       = (ushort*)alloc((size_t)6 * cN2 * 64);
  float* out2       = alloc((size_t)cN2 * 256);

  auto nb = [](long long n) { return (unsigned)((n + 255) / 256); };

  // ---- fused prep: weights + degcnt zero + copyx + out init ----
  prep_all_kernel<<<nb(PREP_ALL_TOTAL), 256, 0, stream>>>(
      W0, W1, W2, W0h, Wt1, Wt2, degcnt, x, Tb0, Ah0, out, linb);

  // ---- two-phase radix CSR build ----
  c1_count_kernel<<<TCB, 256, 0, stream>>>(dst0, dst1, dst2, D0r, D1r,
                                           src0, src1, src2, degcnt, cntCB);
  c2a_scan_kernel<<<TB, 256, 0, stream>>>(cntCB, bucketTot, degcnt, dinv);
  c2b_scan_kernel<<<5, 256, 0, stream>>>(bucketTot, bucketBase);
  c3_dst_kernel<<<TCB, 256, 0, stream>>>(dst0, src0, dst1, src1, dst2, src2,
                                         D0r, D0c, D0v, D1r, D1c, D1v,
                                         dinv, cntCB, bucketBase, scatPairs);
  dcsr_kernel<<<TB, 256, 0, stream>>>(scatPairs, bucketTot, bucketBase,
                                      offArr, csrPairs);

  auto seg_off   = [&](int s) { return offArr + NBASE[s]; };
  auto seg_pairs = [&](int s) { return csrPairs + EBASE[s]; };

  // ================= Level 0 (F=3 -> 128), 4 lanes/row =================
  {
    auto Tk = [&](int k) { return Tb0 + (size_t)k * cN0; };
    csr_prop3_kernel<<<nb((size_t)4 * cN0), 256, 0, stream>>>(seg_off(0), seg_pairs(0),
        Tk(0), Tk(1), nullptr, 1.f, cN0, Ah0, 1);
    csr_prop3_kernel<<<nb((size_t)4 * cN0), 256, 0, stream>>>(seg_off(0), seg_pairs(0),
        Tk(1), Tk(2), Tk(0), 2.f, cN0, Ah0, 2);
    csr_prop3_kernel<<<nb((size_t)4 * cN0), 256, 0, stream>>>(seg_off(0), seg_pairs(0),
        Tk(2), Tk(3), Tk(1), 2.f, cN0, Ah0, 3);
    csr_prop3_kernel<<<nb((size_t)4 * cN0), 256, 0, stream>>>(seg_off(0), seg_pairs(0),
        Tk(3), Tk(4), Tk(2), 2.f, cN0, Ah0, 4);
    csr_prop3_kernel<<<nb((size_t)4 * cN0), 256, 0, stream>>>(seg_off(0), seg_pairs(0),
        Tk(4), Tk(5), Tk(3), 2.f, cN0, Ah0, 5);
  }
  // MFMA h0 (fp16 out), then pool0 fp16 gather -> Tlvl1 block 0
  h0_mfma_kernel<<<(cN0 + 63) / 64, 256, 0, stream>>>(Ah0, W0h, b0, h0h, cN0);
  csr_prop128h_kernel<<<(cN1 + 7) / 8, 256, 0, stream>>>(
      seg_off(3), seg_pairs(3), h0h, Tlvl1, Th1, nullptr, 1.f, cN1);

  // ================= Level 1 =================
  {
    auto Tk  = [&](int k) { return Tlvl1 + (size_t)k * cN1 * 128; };
    auto Thk = [&](int k) { return Th1 + (size_t)k * cN1 * 128; };
    auto prop = [&](int kin, int kout, int kprev, float scale, bool needF32) {
      csr_prop128h_kernel<<<(cN1 + 7) / 8, 256, 0, stream>>>(
          seg_off(1), seg_pairs(1), Thk(kin), needF32 ? Tk(kout) : nullptr, Thk(kout),
          (kprev >= 0) ? Tk(kprev) : nullptr, scale, cN1);
    };
    prop(0, 1, -1, 1.f, true);
    prop(1, 2, 0, 2.f, true);
    prop(2, 3, 1, 2.f, true);
    prop(3, 4, 2, 2.f, true);
    prop(4, 5, 3, 2.f, false);
    dim3 g((cN1 + 63) / 64, 1);
    gemm_mfma_kernel<1, 1><<<g, 256, 0, stream>>>(Th1, Wt1, b1, nullptr, out1h,
                                                  cN1, 128);
  }

  // pool1: out1h (fp16) -> Tlvl2 block 0
  csr_prop128h_kernel<<<(cN2 + 7) / 8, 256, 0, stream>>>(
      seg_off(4), seg_pairs(4), out1h, Tlvl2, Th2, nullptr, 1.f, cN2);

  // ================= Level 2 (no relu, N=256) =================
  {
    auto Tk  = [&](int k) { return Tlvl2 + (size_t)k * cN2 * 128; };
    auto Thk = [&](int k) { return Th2 + (size_t)k * cN2 * 128; };
    auto prop = [&](int kin, int kout, int kprev, float scale, bool needF32) {
      csr_prop128h_kernel<<<(cN2 + 7) / 8, 256, 0, stream>>>(
          seg_off(2), seg_pairs(2), Thk(kin), needF32 ? Tk(kout) : nullptr, Thk(kout),
          (kprev >= 0) ? Tk(kprev) : nullptr, scale, cN2);
    };
    prop(0, 1, -1, 1.f, true);
    prop(1, 2, 0, 2.f, true);
    prop(2, 3, 1, 2.f, true);
    prop(3, 4, 2, 2.f, true);
    prop(4, 5, 3, 2.f, false);
    dim3 g((cN2 + 63) / 64, 2);
    gemm_mfma_kernel<0, 0><<<g, 256, 0, stream>>>(Th2, Wt2, b2, out2, nullptr,
                                                  cN2, 256);
  }

  // ---- linear head (out pre-initialized with linb in prep) ----
  linear_kernel<<<512, 256, 0, stream>>>(linW, out2, out, cD);
}